// Round 10
// baseline (35.934 us; speedup 1.0000x reference)
//
#include <hip/hip_runtime.h>
#include <hip/hip_bf16.h>
#include <math.h>

// Problem constants
#define Bn    8
#define Sn    8
#define COUTc 128
#define PWc   73728
#define Pc    73856
#define WOc   30
#define NPIX  900      // 30*30 per (b,s)
#define GPIX  7200     // B*NPIX per s
#define NSTEP 9        // one r=(ky,kx) per K-step, 64 ci each
#define TILE  64       // pixels per block
#define NTIL  113      // ceil(7200/64)

typedef __bf16 bf16;
typedef bf16  bf16x8 __attribute__((ext_vector_type(8)));
typedef float f32x16 __attribute__((ext_vector_type(16)));

__device__ __forceinline__ float softplus_f(float x) {
    return fmaxf(x, 0.f) + log1pf(expf(-fabsf(x)));
}

__device__ __forceinline__ unsigned int pack2(float a, float b) {
    unsigned short ua = __builtin_bit_cast(unsigned short, (bf16)a);
    unsigned short ub = __builtin_bit_cast(unsigned short, (bf16)b);
    return ((unsigned int)ub << 16) | (unsigned int)ua;
}

// global->LDS direct copy, 16B per lane. LDS dest = wave-uniform base
// (+ implicit lane*16); global src is per-lane.
__device__ __forceinline__ void gl16(const void* g, void* l) {
    typedef __attribute__((address_space(1))) void gvoid;
    typedef __attribute__((address_space(3))) void lvoid;
    __builtin_amdgcn_global_load_lds((gvoid*)g, (lvoid*)l, 16, 0, 0);
}

// ---------------------------------------------------------------------------
// Kernel 1 (fused) — identical to the proven 30.2 µs version:
//  blocks 0..511  : xcast  x fp32 NCHW -> xt bf16 channels-last [img][yx][ci]
//  blocks 512..543: W sampling, thread = (co,ci), 9 contiguous taps, into the
//                   swizzled per-(s,r) LDS images
//  block  544     : bias sampling
//  Prep blocks write KL partials to slots[33*2] unconditionally.
//  wimg page (s,r): element (co<<6) + (((ci>>3)^(co&7))<<3) + (ci&7).
// ---------------------------------------------------------------------------
__global__ __launch_bounds__(256) void prep_all(
        const float* __restrict__ xg, const float* __restrict__ e,
        const float* __restrict__ mu_w, const float* __restrict__ rho_w,
        const float* __restrict__ mu_b, const float* __restrict__ rho_b,
        bf16* __restrict__ xt, bf16* __restrict__ wimg,
        float* __restrict__ bq, float* __restrict__ slots) {
    const int bid = blockIdx.x;
    const int t   = threadIdx.x;

    if (bid < 512) {  // ---- xcast
        const int img  = bid >> 3;
        const int part = bid & 7;
        const int p    = part * 128 + (t >> 1);
        const int half = t & 1;
        const float* src = xg + ((size_t)img << 16) + (size_t)(half * 32) * 1024 + p;
        bf16*        dst = xt + ((size_t)img << 16) + (size_t)p * 64 + half * 32;
        #pragma unroll
        for (int o = 0; o < 4; ++o) {
            uint4 pk;
            pk.x = pack2(src[(o * 8 + 0) * 1024], src[(o * 8 + 1) * 1024]);
            pk.y = pack2(src[(o * 8 + 2) * 1024], src[(o * 8 + 3) * 1024]);
            pk.z = pack2(src[(o * 8 + 4) * 1024], src[(o * 8 + 5) * 1024]);
            pk.w = pack2(src[(o * 8 + 6) * 1024], src[(o * 8 + 7) * 1024]);
            *reinterpret_cast<uint4*>(dst + o * 8) = pk;
        }
        return;
    }

    float ls = 0.f, sq = 0.f;
    if (bid < 544) {  // ---- W prep: thread = one (co,ci) pair, 9 taps
        const int gidx = (bid - 512) * 256 + t;   // 0..8191
        const int co   = gidx >> 6;
        const int ci   = gidx & 63;
        const int p0   = co * 576 + ci * 9;
        float mu[9], sg[9];
        #pragma unroll
        for (int r = 0; r < 9; ++r) {
            mu[r] = mu_w[p0 + r];
            sg[r] = softplus_f(rho_w[p0 + r]);
            ls   += logf(sg[r]);
        }
        const int dstp = (co << 6) + (((ci >> 3) ^ (co & 7)) << 3) + (ci & 7);
        #pragma unroll
        for (int s = 0; s < Sn; ++s) {
            const float* es = e + s * Pc + p0;
            #pragma unroll
            for (int r = 0; r < 9; ++r) {
                float wv = fmaf(sg[r], es[r], mu[r]);
                wimg[((s * NSTEP + r) << 13) + dstp] = (bf16)wv;
                sq += wv * wv;
            }
        }
    } else {          // ---- bias prep (bid == 544)
        if (t < COUTc) {
            float sig = softplus_f(rho_b[t]);
            ls = logf(sig);
            float mu = mu_b[t];
            #pragma unroll
            for (int s = 0; s < Sn; ++s) {
                float bv = fmaf(sig, e[s * Pc + PWc + t], mu);
                bq[s * COUTc + t] = bv;
                sq += bv * bv;
            }
        }
    }

    #pragma unroll
    for (int off = 32; off > 0; off >>= 1) {
        ls += __shfl_down(ls, off);
        sq += __shfl_down(sq, off);
    }
    __shared__ float sls[4], ssq[4];
    const int lane = t & 63, wd = t >> 6;
    if (lane == 0) { sls[wd] = ls; ssq[wd] = sq; }
    __syncthreads();
    if (t == 0) {
        slots[2 * (bid - 512)]     = sls[0] + sls[1] + sls[2] + sls[3];
        slots[2 * (bid - 512) + 1] = ssq[0] + ssq[1] + ssq[2] + ssq[3];
    }
}

// ---------------------------------------------------------------------------
// Kernel 2: implicit-GEMM conv — R5's proven depth-2 counted-vmcnt schedule,
// with TILE=64 (block 128co x 64pix, 4 waves 2x2 of 64co x 32pix).
// LDS 48 KB dbuf (W 2x16 KB + X 2x8 KB) -> 3 blocks/CU, ~12 waves/CU.
// STAGE = 6 gl16/wave -> counted wait vmcnt(6) (oldest stage complete,
// newest stays in flight). All staging via global_load_lds with the XOR
// swizzle pre-baked in the global sources. s = bid&7 -> XCD-affine.
// KL finalize folded into block 0.
// ---------------------------------------------------------------------------
__global__ __launch_bounds__(256) void conv_mfma(
        const bf16* __restrict__ xt, const bf16* __restrict__ wimg,
        const float* __restrict__ bq, const float* __restrict__ slots,
        float* __restrict__ out, float* __restrict__ klout) {
    const int bid  = blockIdx.x;
    const int s    = bid & 7;
    const int tile = bid >> 3;
    const int t    = threadIdx.x;
    const int lane = t & 63;
    const int w    = t >> 6;
    const int wr   = w >> 1;     // co half (0/1)
    const int wc   = w & 1;      // pix half (0/1)

    __shared__ bf16 Wbuf[2][8192];   // 2 x 16 KB  [co 0..127][ci-oct swz]
    __shared__ bf16 Xbuf[2][4096];   // 2 x  8 KB  [pix 0..63][ci-oct swz]

    // W staging source: wimg page is the exact LDS byte image
    const char* wsrcL = (const char*)wimg + ((size_t)(s * NSTEP) << 14)
                      + (w << 12) + (lane << 4);

    // X staging sources: wave w stages pix rows [w*16, w*16+16), 2 gl16
    const char *x0, *x1;
    #pragma unroll
    for (int q = 0; q < 2; ++q) {
        int pix = w * 16 + q * 8 + (lane >> 3);
        int g   = tile * TILE + pix;
        if (g >= GPIX) g = GPIX - 1;      // clamp; garbage cols discarded
        int b2 = g / NPIX, rr = g - b2 * NPIX, oy = rr / WOc, ox = rr - oy * WOc;
        int m  = (lane & 7) ^ (pix & 7);  // source ci-octet for this slot
        const char* ptr = (const char*)xt
            + ((((size_t)(b2 * Sn + s) << 10) + oy * 32 + ox) << 7) + (m << 4);
        if (q == 0) x0 = ptr; else x1 = ptr;
    }

    f32x16 acc[2];
    #pragma unroll
    for (int i = 0; i < 2; ++i)
        #pragma unroll
        for (int k = 0; k < 16; ++k)
            acc[i][k] = 0.f;

    #define STAGE(stepc, b)                                                  \
    {                                                                        \
        const char* ws_ = wsrcL + ((stepc) << 14);                           \
        char* wl_ = (char*)(&Wbuf[(b)][0]) + (w << 12);                      \
        gl16(ws_,        wl_);                                               \
        gl16(ws_ + 1024, wl_ + 1024);                                        \
        gl16(ws_ + 2048, wl_ + 2048);                                        \
        gl16(ws_ + 3072, wl_ + 3072);                                        \
        const int roff_ = (((stepc) / 3) * 32 + ((stepc) % 3)) * 128;        \
        char* xl_ = (char*)(&Xbuf[(b)][0]) + (w << 11);                      \
        gl16(x0 + roff_, xl_);                                               \
        gl16(x1 + roff_, xl_ + 1024);                                        \
    }

    #define COMPUTE(b)                                                       \
    {                                                                        \
        const bf16* Wl_ = &Wbuf[(b)][0];                                     \
        const bf16* Xl_ = &Xbuf[(b)][0];                                     \
        _Pragma("unroll")                                                    \
        for (int kc = 0; kc < 4; ++kc) {                                     \
            const int oct_ = ((kc << 1) + (lane >> 5)) ^ (lane & 7);         \
            bf16x8 af0 = *reinterpret_cast<const bf16x8*>(                   \
                Wl_ + ((wr * 64 + (lane & 31)) << 6) + (oct_ << 3));         \
            bf16x8 af1 = *reinterpret_cast<const bf16x8*>(                   \
                Wl_ + ((wr * 64 + 32 + (lane & 31)) << 6) + (oct_ << 3));    \
            bf16x8 bf0 = *reinterpret_cast<const bf16x8*>(                   \
                Xl_ + ((wc * 32 + (lane & 31)) << 6) + (oct_ << 3));         \
            acc[0] = __builtin_amdgcn_mfma_f32_32x32x16_bf16(af0, bf0, acc[0], 0, 0, 0); \
            acc[1] = __builtin_amdgcn_mfma_f32_32x32x16_bf16(af1, bf0, acc[1], 0, 0, 0); \
        }                                                                    \
    }

    // prologue: two stages in flight
    STAGE(0, 0);
    STAGE(1, 1);

    #define ITER(tt, b)                                                      \
        asm volatile("s_waitcnt vmcnt(6)" ::: "memory");                     \
        __builtin_amdgcn_s_barrier();                                        \
        __builtin_amdgcn_sched_barrier(0);                                   \
        COMPUTE(b);                                                          \
        __builtin_amdgcn_sched_barrier(0);                                   \
        __builtin_amdgcn_s_barrier();                                        \
        STAGE((tt) + 2, b);

    ITER(0, 0)
    ITER(1, 1)
    ITER(2, 0)
    ITER(3, 1)
    ITER(4, 0)
    ITER(5, 1)
    ITER(6, 0)
    // step 7 (buf 1): no further stage
    asm volatile("s_waitcnt vmcnt(6)" ::: "memory");
    __builtin_amdgcn_s_barrier();
    __builtin_amdgcn_sched_barrier(0);
    COMPUTE(1);
    // step 8 (buf 0): final, drain
    asm volatile("s_waitcnt vmcnt(0)" ::: "memory");
    __builtin_amdgcn_s_barrier();
    __builtin_amdgcn_sched_barrier(0);
    COMPUTE(0);

    #undef ITER
    #undef COMPUTE
    #undef STAGE

    // ---- epilogue: 32x32 C/D: col(pix)=lane&31, row(co)=(reg&3)+8*(reg>>2)+4*(lane>>5)
    const int colp = lane & 31;
    const int hi   = lane >> 5;
    const int gg   = tile * TILE + wc * 32 + colp;
    if (gg < GPIX) {
        const int b2 = gg / NPIX;
        const int r2 = gg - b2 * NPIX;
        float* ob = out + (size_t)(b2 * Sn + s) * (COUTc * NPIX) + r2;
        #pragma unroll
        for (int ti = 0; ti < 2; ++ti) {
            #pragma unroll
            for (int reg = 0; reg < 16; ++reg) {
                int co = wr * 64 + ti * 32 + (reg & 3) + 8 * (reg >> 2) + 4 * hi;
                ob[co * NPIX] = acc[ti][reg] + bq[s * COUTc + co];
            }
        }
    }

    // ---- KL finalize (block 0): sum the 33 partial slots
    if (bid == 0 && t == 0) {
        float ls = 0.f, sq = 0.f;
        for (int i2 = 0; i2 < 33; ++i2) {
            ls += slots[2 * i2];
            sq += slots[2 * i2 + 1];
        }
        *klout = -ls + 0.91893853320467274f * (float)Pc + 0.5f * sq;
    }
}

// ---------------------------------------------------------------------------
extern "C" void kernel_launch(void* const* d_in, const int* in_sizes, int n_in,
                              void* d_out, int out_size, void* d_ws, size_t ws_size,
                              hipStream_t stream) {
    const float* x     = (const float*)d_in[0];
    const float* e     = (const float*)d_in[1];
    const float* mu_w  = (const float*)d_in[2];
    const float* rho_w = (const float*)d_in[3];
    const float* mu_b  = (const float*)d_in[4];
    const float* rho_b = (const float*)d_in[5];
    float* out = (float*)d_out;

    // workspace layout
    bf16*  wimg  = (bf16*)d_ws;                         // 1,179,648 B
    float* bq    = (float*)((char*)d_ws + 1179648);     // 4,096 B
    float* slots = (float*)((char*)d_ws + 1183744);     // 264 B (pad to 4K)
    bf16*  xt    = (bf16*)((char*)d_ws + 1187840);      // 8,388,608 B

    prep_all<<<dim3(545), dim3(256), 0, stream>>>(
        x, e, mu_w, rho_w, mu_b, rho_b, xt, wimg, bq, slots);

    conv_mfma<<<dim3(NTIL * Sn), dim3(256), 0, stream>>>(
        xt, wimg, bq, slots, out, out + (out_size - 1));
}

// Round 11
// 34.725 us; speedup vs baseline: 1.0348x; 1.0348x over previous
//
#include <hip/hip_runtime.h>
#include <hip/hip_bf16.h>
#include <math.h>

// Problem constants
#define Bn    8
#define Sn    8
#define COUTc 128
#define PWc   73728
#define Pc    73856
#define WOc   30
#define NPIX  900      // 30*30 per (b,s)
#define GPIX  7200     // B*NPIX per s
#define NSTEP 9        // one r=(ky,kx) per K-step, 64 ci each
#define TILE  128      // pixels per block
#define NT2   57       // ceil(7200/128)
#define WSLOTS 10                 // input row slots in the halo window
#define XPLANE (WSLOTS * 32 * 16) // 5120 B per ci-octet plane
#define XLDSB  (8 * XPLANE)       // 40960 B window

typedef __bf16 bf16;
typedef bf16  bf16x8 __attribute__((ext_vector_type(8)));
typedef float f32x4v __attribute__((ext_vector_type(4)));
typedef float f32x16 __attribute__((ext_vector_type(16)));

__device__ __forceinline__ float softplus_f(float x) {
    return fmaxf(x, 0.f) + log1pf(expf(-fabsf(x)));
}

__device__ __forceinline__ unsigned int pack2(float a, float b) {
    unsigned short ua = __builtin_bit_cast(unsigned short, (bf16)a);
    unsigned short ub = __builtin_bit_cast(unsigned short, (bf16)b);
    return ((unsigned int)ub << 16) | (unsigned int)ua;
}

// global->LDS direct copy, 16B per lane. LDS dest = wave-uniform base
// (+ implicit lane*16); global src is per-lane.
__device__ __forceinline__ void gl16(const void* g, void* l) {
    typedef __attribute__((address_space(1))) void gvoid;
    typedef __attribute__((address_space(3))) void lvoid;
    __builtin_amdgcn_global_load_lds((gvoid*)g, (lvoid*)l, 16, 0, 0);
}

// ---------------------------------------------------------------------------
// Kernel 1 (fused):
//  blocks 0..511  : xcast  x fp32 NCHW -> xt bf16 OCT-MAJOR [img][oct][yx]
//                   (byte: img*131072 + oct*16384 + yx*16; 16B = 8 ci)
//  blocks 512..543: W sampling, thread = (co,ci), 9 contiguous taps, into the
//                   swizzled per-(s,r) LDS images (proven R5 layout)
//  block  544     : bias sampling
//  Prep blocks write KL partials to slots[33*2] unconditionally.
//  wimg page (s,r): element (co<<6) + (((ci>>3)^(co&7))<<3) + (ci&7).
// ---------------------------------------------------------------------------
__global__ __launch_bounds__(256) void prep_all(
        const float* __restrict__ xg, const float* __restrict__ e,
        const float* __restrict__ mu_w, const float* __restrict__ rho_w,
        const float* __restrict__ mu_b, const float* __restrict__ rho_b,
        bf16* __restrict__ xt, bf16* __restrict__ wimg,
        float* __restrict__ bq, float* __restrict__ slots) {
    const int bid = blockIdx.x;
    const int t   = threadIdx.x;

    if (bid < 512) {  // ---- xcast: thread = (oct, 4 consecutive pixels)
        const int img  = bid >> 3;
        const int part = bid & 7;
        const int oct  = t >> 5;
        const int p0   = part * 128 + (t & 31) * 4;
        const float* src = xg + ((size_t)img << 16) + (size_t)(oct * 8) * 1024 + p0;
        f32x4v v0 = *reinterpret_cast<const f32x4v*>(src);
        f32x4v v1 = *reinterpret_cast<const f32x4v*>(src + 1024);
        f32x4v v2 = *reinterpret_cast<const f32x4v*>(src + 2048);
        f32x4v v3 = *reinterpret_cast<const f32x4v*>(src + 3072);
        f32x4v v4 = *reinterpret_cast<const f32x4v*>(src + 4096);
        f32x4v v5 = *reinterpret_cast<const f32x4v*>(src + 5120);
        f32x4v v6 = *reinterpret_cast<const f32x4v*>(src + 6144);
        f32x4v v7 = *reinterpret_cast<const f32x4v*>(src + 7168);
        char* dst = (char*)xt + (size_t)img * 131072 + oct * 16384 + p0 * 16;
        #pragma unroll
        for (int i = 0; i < 4; ++i) {
            uint4 pk;
            pk.x = pack2(v0[i], v1[i]);
            pk.y = pack2(v2[i], v3[i]);
            pk.z = pack2(v4[i], v5[i]);
            pk.w = pack2(v6[i], v7[i]);
            *reinterpret_cast<uint4*>(dst + i * 16) = pk;
        }
        return;
    }

    float ls = 0.f, sq = 0.f;
    if (bid < 544) {  // ---- W prep: thread = one (co,ci) pair, 9 taps
        const int gidx = (bid - 512) * 256 + t;   // 0..8191
        const int co   = gidx >> 6;
        const int ci   = gidx & 63;
        const int p0   = co * 576 + ci * 9;
        float mu[9], sg[9];
        #pragma unroll
        for (int r = 0; r < 9; ++r) {
            mu[r] = mu_w[p0 + r];
            sg[r] = softplus_f(rho_w[p0 + r]);
            ls   += logf(sg[r]);
        }
        const int dstp = (co << 6) + (((ci >> 3) ^ (co & 7)) << 3) + (ci & 7);
        #pragma unroll
        for (int s = 0; s < Sn; ++s) {
            const float* es = e + s * Pc + p0;
            #pragma unroll
            for (int r = 0; r < 9; ++r) {
                float wv = fmaf(sg[r], es[r], mu[r]);
                wimg[((s * NSTEP + r) << 13) + dstp] = (bf16)wv;
                sq += wv * wv;
            }
        }
    } else {          // ---- bias prep (bid == 544)
        if (t < COUTc) {
            float sig = softplus_f(rho_b[t]);
            ls = logf(sig);
            float mu = mu_b[t];
            #pragma unroll
            for (int s = 0; s < Sn; ++s) {
                float bv = fmaf(sig, e[s * Pc + PWc + t], mu);
                bq[s * COUTc + t] = bv;
                sq += bv * bv;
            }
        }
    }

    #pragma unroll
    for (int off = 32; off > 0; off >>= 1) {
        ls += __shfl_down(ls, off);
        sq += __shfl_down(sq, off);
    }
    __shared__ float sls[4], ssq[4];
    const int lane = t & 63, wd = t >> 6;
    if (lane == 0) { sls[wd] = ls; ssq[wd] = sq; }
    __syncthreads();
    if (t == 0) {
        slots[2 * (bid - 512)]     = sls[0] + sls[1] + sls[2] + sls[3];
        slots[2 * (bid - 512) + 1] = ssq[0] + ssq[1] + ssq[2] + ssq[3];
    }
}

// ---------------------------------------------------------------------------
// Kernel 2: implicit-GEMM conv — R5 geometry (128co x 128pix, 4 waves 2x2,
// mfma_f32_32x32x16_bf16, depth-2 counted-vmcnt ladder) with the X halo
// window staged ONCE (40 KB, 10 row slots, oct-major) and only W staged
// per step (4 gl16/wave -> vmcnt(4)). X B-frag reads use per-lane base +
// compile-time ds_read immediate offsets. LDS = 32 KB Wdbuf + 40 KB Xw
// -> 2 blocks/CU. s = bid&7 XCD-affine; KL finalize in block 0.
// ---------------------------------------------------------------------------
__global__ __launch_bounds__(256) void conv_mfma(
        const bf16* __restrict__ xt, const bf16* __restrict__ wimg,
        const float* __restrict__ bq, const float* __restrict__ slots,
        float* __restrict__ out, float* __restrict__ klout) {
    const int bid  = blockIdx.x;
    const int s    = bid & 7;
    const int tile = bid >> 3;
    const int t    = threadIdx.x;
    const int lane = t & 63;
    const int w    = t >> 6;
    const int wr   = w >> 1;     // co half (0/1)
    const int wc   = w & 1;      // pix half (0/1)
    const int hi   = lane >> 5;
    const int lo   = lane & 31;

    __shared__ bf16 Wbuf[2][8192];   // 2 x 16 KB  [co 0..127][ci-oct swz]
    __shared__ char Xw[XLDSB];       // 40 KB halo window [oct][slot*32+ix]

    // ---- window geometry (block-uniform)
    const int g0 = tile * TILE;
    const int R0 = g0 / 30;          // first global output row
    const int bA = R0 / 30;          // first batch
    const int rA = R0 - bA * 30;     // first output row within batch A
    const int nA = 30 - rA;          // output rows of batch A in window
    const bool crossing = (rA >= 25);

    // ---- W staging source: wimg page is the exact LDS byte image
    const char* wsrcL = (const char*)wimg + ((size_t)(s * NSTEP) << 14)
                      + (w << 12) + (lane << 4);

    #define STAGEW(stepc, b)                                                 \
    {                                                                        \
        const char* ws_ = wsrcL + ((stepc) << 14);                           \
        char* wl_ = (char*)(&Wbuf[(b)][0]) + (w << 12);                      \
        gl16(ws_,        wl_);                                               \
        gl16(ws_ + 1024, wl_ + 1024);                                        \
        gl16(ws_ + 2048, wl_ + 2048);                                        \
        gl16(ws_ + 3072, wl_ + 3072);                                        \
    }

    // ---- X window staging: wave w stages octs {2w, 2w+1}, 5 gl16 each.
    // Window slot k: k < nA+2 -> (bA, rA+k) else (bA+1, k-nA-2); clamped.
    {
        const char* xtB = (const char*)xt;
        #pragma unroll
        for (int r = 0; r < 5; ++r) {
            int slot = 2 * r + hi;
            int b, iy;
            if (crossing && slot >= nA + 2) { b = bA + 1; iy = slot - nA - 2; }
            else { b = bA; iy = rA + slot; if (iy > 31) iy = 31; }
            if (b > 7) b = 7;
            const char* src = xtB + (size_t)(b * 8 + s) * 131072
                            + (size_t)(w * 2) * 16384 + (iy * 32 + lo) * 16;
            gl16(src,         Xw + (w * 2) * XPLANE + r * 1024);
            gl16(src + 16384, Xw + (w * 2 + 1) * XPLANE + r * 1024);
        }
    }

    // stage W for steps 0,1 (after X: vmcnt(4) => X + W0 complete)
    STAGEW(0, 0);
    STAGEW(1, 1);

    // ---- per-lane X B-frag byte bases (two 32-pix column groups)
    int xb0, xb1;
    #pragma unroll
    for (int j = 0; j < 2; ++j) {
        int g = g0 + wc * 64 + j * 32 + lo;
        if (g > GPIX - 1) g = GPIX - 1;
        int R = g / 30, col = g - R * 30;
        int b = R / 30, oy = R - b * 30;
        int slot0 = (b == bA) ? (oy - rA) : (nA + 2 + oy);
        int base = hi * XPLANE + (slot0 * 32 + col) * 16;
        if (j == 0) xb0 = base; else xb1 = base;
    }

    f32x16 acc00, acc01, acc10, acc11;
    #pragma unroll
    for (int k = 0; k < 16; ++k) {
        acc00[k] = 0.f; acc01[k] = 0.f; acc10[k] = 0.f; acc11[k] = 0.f;
    }

    #define COMPUTE(b, KY, KX)                                               \
    {                                                                        \
        const bf16* Wl_ = &Wbuf[(b)][0];                                     \
        _Pragma("unroll")                                                    \
        for (int kc = 0; kc < 4; ++kc) {                                     \
            const int oct_ = ((kc << 1) + hi) ^ (lane & 7);                  \
            bf16x8 af0 = *reinterpret_cast<const bf16x8*>(                   \
                Wl_ + ((wr * 64 + lo) << 6) + (oct_ << 3));                  \
            bf16x8 af1 = *reinterpret_cast<const bf16x8*>(                   \
                Wl_ + ((wr * 64 + 32 + lo) << 6) + (oct_ << 3));             \
            bf16x8 bf0 = *reinterpret_cast<const bf16x8*>(                   \
                Xw + xb0 + kc * (2 * XPLANE) + ((KY) * 512 + (KX) * 16));    \
            bf16x8 bf1 = *reinterpret_cast<const bf16x8*>(                   \
                Xw + xb1 + kc * (2 * XPLANE) + ((KY) * 512 + (KX) * 16));    \
            acc00 = __builtin_amdgcn_mfma_f32_32x32x16_bf16(af0, bf0, acc00, 0, 0, 0); \
            acc01 = __builtin_amdgcn_mfma_f32_32x32x16_bf16(af0, bf1, acc01, 0, 0, 0); \
            acc10 = __builtin_amdgcn_mfma_f32_32x32x16_bf16(af1, bf0, acc10, 0, 0, 0); \
            acc11 = __builtin_amdgcn_mfma_f32_32x32x16_bf16(af1, bf1, acc11, 0, 0, 0); \
        }                                                                    \
    }

    #define ITER(tt, b)                                                      \
        asm volatile("s_waitcnt vmcnt(4)" ::: "memory");                     \
        __builtin_amdgcn_s_barrier();                                        \
        __builtin_amdgcn_sched_barrier(0);                                   \
        COMPUTE(b, (tt) / 3, (tt) % 3);                                      \
        __builtin_amdgcn_sched_barrier(0);                                   \
        __builtin_amdgcn_s_barrier();                                        \
        STAGEW((tt) + 2, b);

    ITER(0, 0)
    ITER(1, 1)
    ITER(2, 0)
    ITER(3, 1)
    ITER(4, 0)
    ITER(5, 1)
    ITER(6, 0)
    // step 7 (buf 1): no further stage
    asm volatile("s_waitcnt vmcnt(4)" ::: "memory");
    __builtin_amdgcn_s_barrier();
    __builtin_amdgcn_sched_barrier(0);
    COMPUTE(1, 2, 1);
    // step 8 (buf 0): final, drain
    asm volatile("s_waitcnt vmcnt(0)" ::: "memory");
    __builtin_amdgcn_s_barrier();
    __builtin_amdgcn_sched_barrier(0);
    COMPUTE(0, 2, 2);

    #undef ITER
    #undef COMPUTE
    #undef STAGEW

    // ---- epilogue: 32x32 C/D: col(pix)=lane&31, row(co)=(reg&3)+8*(reg>>2)+4*hi
    #pragma unroll
    for (int ti = 0; ti < 2; ++ti) {
        float bs[16];
        #pragma unroll
        for (int reg = 0; reg < 16; ++reg) {
            int co = wr * 64 + ti * 32 + (reg & 3) + 8 * (reg >> 2) + 4 * hi;
            bs[reg] = bq[s * COUTc + co];
        }
        #pragma unroll
        for (int tj = 0; tj < 2; ++tj) {
            const f32x16& av = ti ? (tj ? acc11 : acc10) : (tj ? acc01 : acc00);
            int gg = tile * TILE + wc * 64 + tj * 32 + lo;
            if (gg >= GPIX) continue;
            int b2 = gg / NPIX;
            int r2 = gg - b2 * NPIX;
            float* ob = out + (size_t)(b2 * Sn + s) * (COUTc * NPIX) + r2;
            #pragma unroll
            for (int reg = 0; reg < 16; ++reg) {
                int co = wr * 64 + ti * 32 + (reg & 3) + 8 * (reg >> 2) + 4 * hi;
                ob[co * NPIX] = av[reg] + bs[reg];
            }
        }
    }

    // ---- KL finalize (block 0): sum the 33 partial slots
    if (bid == 0 && t == 0) {
        float ls = 0.f, sq = 0.f;
        for (int i2 = 0; i2 < 33; ++i2) {
            ls += slots[2 * i2];
            sq += slots[2 * i2 + 1];
        }
        *klout = -ls + 0.91893853320467274f * (float)Pc + 0.5f * sq;
    }
}

// ---------------------------------------------------------------------------
extern "C" void kernel_launch(void* const* d_in, const int* in_sizes, int n_in,
                              void* d_out, int out_size, void* d_ws, size_t ws_size,
                              hipStream_t stream) {
    const float* x     = (const float*)d_in[0];
    const float* e     = (const float*)d_in[1];
    const float* mu_w  = (const float*)d_in[2];
    const float* rho_w = (const float*)d_in[3];
    const float* mu_b  = (const float*)d_in[4];
    const float* rho_b = (const float*)d_in[5];
    float* out = (float*)d_out;

    // workspace layout
    bf16*  wimg  = (bf16*)d_ws;                         // 1,179,648 B
    float* bq    = (float*)((char*)d_ws + 1179648);     // 4,096 B
    float* slots = (float*)((char*)d_ws + 1183744);     // 264 B (pad to 4K)
    bf16*  xt    = (bf16*)((char*)d_ws + 1187840);      // 8,388,608 B oct-major

    prep_all<<<dim3(545), dim3(256), 0, stream>>>(
        x, e, mu_w, rho_w, mu_b, rho_b, xt, wimg, bq, slots);

    conv_mfma<<<dim3(NT2 * Sn), dim3(256), 0, stream>>>(
        xt, wimg, bq, slots, out, out + (out_size - 1));
}

// Round 12
// 30.848 us; speedup vs baseline: 1.1649x; 1.1257x over previous
//
#include <hip/hip_runtime.h>
#include <hip/hip_bf16.h>
#include <math.h>

// Problem constants
#define Bn    8
#define Sn    8
#define COUTc 128
#define PWc   73728
#define Pc    73856
#define WOc   30
#define NPIX  900      // 30*30 per (b,s)
#define GPIX  7200     // B*NPIX per s
#define NSTEP 9        // one r=(ky,kx) per K-step, 64 ci each
#define TILE  128      // pixels per block
#define NT2   57       // ceil(7200/128)
#define NSLOT 129      // 128 W-prep blocks + 1 bias block

typedef __bf16 bf16;
typedef bf16  bf16x8 __attribute__((ext_vector_type(8)));
typedef float f32x4v __attribute__((ext_vector_type(4)));
typedef float f32x16 __attribute__((ext_vector_type(16)));

__device__ __forceinline__ float softplus_f(float x) {
    return fmaxf(x, 0.f) + log1pf(expf(-fabsf(x)));
}

__device__ __forceinline__ unsigned int pack2(float a, float b) {
    unsigned short ua = __builtin_bit_cast(unsigned short, (bf16)a);
    unsigned short ub = __builtin_bit_cast(unsigned short, (bf16)b);
    return ((unsigned int)ub << 16) | (unsigned int)ua;
}

// global->LDS direct copy, 16B per lane. LDS dest = wave-uniform base
// (+ implicit lane*16); global src is per-lane.
__device__ __forceinline__ void gl16(const void* g, void* l) {
    typedef __attribute__((address_space(1))) void gvoid;
    typedef __attribute__((address_space(3))) void lvoid;
    __builtin_amdgcn_global_load_lds((gvoid*)g, (lvoid*)l, 16, 0, 0);
}

// ---------------------------------------------------------------------------
// Kernel 1 (fused):
//  blocks 0..511  : xcast  x fp32 NCHW -> xt bf16 channels-last [img][yx][ci]
//                   12 VMEM/thread: 8 float4 loads + 4 uint4 stores
//  blocks 512..639: W sampling. Block = (s-pair, chunk); thread = (co,ci),
//                   9 contiguous taps, 2 samples. log(sig) counted only by
//                   s-group 0. Dest = swizzled per-(s,r) LDS images.
//  block  640     : bias sampling
//  All prep blocks write KL partials to slots[NSLOT*2] unconditionally.
//  wimg page (s,r): element (co<<6) + (((ci>>3)^(co&7))<<3) + (ci&7).
// ---------------------------------------------------------------------------
__global__ __launch_bounds__(256) void prep_all(
        const float* __restrict__ xg, const float* __restrict__ e,
        const float* __restrict__ mu_w, const float* __restrict__ rho_w,
        const float* __restrict__ mu_b, const float* __restrict__ rho_b,
        bf16* __restrict__ xt, bf16* __restrict__ wimg,
        float* __restrict__ bq, float* __restrict__ slots) {
    const int bid = blockIdx.x;
    const int t   = threadIdx.x;

    if (bid < 512) {  // ---- xcast: thread = (oct, 4 consecutive pixels)
        const int img = bid >> 3;
        const int oct = t & 7;                           // ci octet
        const int p0  = ((bid & 7) * 32 + (t >> 3)) * 4; // yx 0..1020
        const float* src = xg + ((size_t)img << 16) + (size_t)(oct * 8) * 1024 + p0;
        f32x4v v[8];
        #pragma unroll
        for (int j = 0; j < 8; ++j)
            v[j] = *reinterpret_cast<const f32x4v*>(src + (size_t)j * 1024);
        // dst: [img][p][ci] channels-last, 128 B per pixel, 16 B per octet
        char* dstB = (char*)xt + (((size_t)(img << 10) + p0) << 7) + (oct << 4);
        #pragma unroll
        for (int i = 0; i < 4; ++i) {
            uint4 pk;
            pk.x = pack2(v[0][i], v[1][i]);
            pk.y = pack2(v[2][i], v[3][i]);
            pk.z = pack2(v[4][i], v[5][i]);
            pk.w = pack2(v[6][i], v[7][i]);
            *reinterpret_cast<uint4*>(dstB + (size_t)i * 128) = pk;
        }
        return;
    }

    float ls = 0.f, sq = 0.f;
    if (bid < 640) {  // ---- W prep: block = (s-group, chunk); 2 samples each
        const int rb    = bid - 512;
        const int sg2   = rb >> 5;          // s-group 0..3 -> samples {2g,2g+1}
        const int chunk = rb & 31;
        const int gidx  = chunk * 256 + t;  // 0..8191 (co,ci)
        const int co    = gidx >> 6;
        const int ci    = gidx & 63;
        const int p0    = co * 576 + ci * 9;
        float mu[9], sg[9];
        #pragma unroll
        for (int r = 0; r < 9; ++r) {
            mu[r] = mu_w[p0 + r];
            sg[r] = softplus_f(rho_w[p0 + r]);
        }
        if (sg2 == 0) {
            #pragma unroll
            for (int r = 0; r < 9; ++r) ls += logf(sg[r]);
        }
        const int dstp = (co << 6) + (((ci >> 3) ^ (co & 7)) << 3) + (ci & 7);
        #pragma unroll
        for (int si = 0; si < 2; ++si) {
            const int s = sg2 * 2 + si;
            const float* es = e + s * Pc + p0;
            #pragma unroll
            for (int r = 0; r < 9; ++r) {
                float wv = fmaf(sg[r], es[r], mu[r]);
                wimg[((s * NSTEP + r) << 13) + dstp] = (bf16)wv;
                sq += wv * wv;
            }
        }
    } else {          // ---- bias prep (bid == 640)
        if (t < COUTc) {
            float sig = softplus_f(rho_b[t]);
            ls = logf(sig);
            float mu = mu_b[t];
            #pragma unroll
            for (int s = 0; s < Sn; ++s) {
                float bv = fmaf(sig, e[s * Pc + PWc + t], mu);
                bq[s * COUTc + t] = bv;
                sq += bv * bv;
            }
        }
    }

    #pragma unroll
    for (int off = 32; off > 0; off >>= 1) {
        ls += __shfl_down(ls, off);
        sq += __shfl_down(sq, off);
    }
    __shared__ float sls[4], ssq[4];
    const int lane = t & 63, wd = t >> 6;
    if (lane == 0) { sls[wd] = ls; ssq[wd] = sq; }
    __syncthreads();
    if (t == 0) {
        slots[2 * (bid - 512)]     = sls[0] + sls[1] + sls[2] + sls[3];
        slots[2 * (bid - 512) + 1] = ssq[0] + ssq[1] + ssq[2] + ssq[3];
    }
}

// ---------------------------------------------------------------------------
// Kernel 2: implicit-GEMM conv — the proven 30.2 µs R5 kernel, verbatim.
// Block = 256 thr (4 waves 2x2 of 64co x 64pix), tile 128co x 128pix,
// mfma_f32_32x32x16_bf16, BK=64 (one r per step). Double-buffered LDS
// (64 KB), all staging via global_load_lds with the XOR swizzle pre-baked
// in the global sources; counted vmcnt(8) + raw s_barrier, depth-2.
// s = bid&7 -> XCD-affine. KL finalize (wave-parallel) in block 0.
// ---------------------------------------------------------------------------
__global__ __launch_bounds__(256) void conv_mfma(
        const bf16* __restrict__ xt, const bf16* __restrict__ wimg,
        const float* __restrict__ bq, const float* __restrict__ slots,
        float* __restrict__ out, float* __restrict__ klout) {
    const int bid  = blockIdx.x;
    const int s    = bid & 7;
    const int tile = bid >> 3;
    const int t    = threadIdx.x;
    const int lane = t & 63;
    const int w    = t >> 6;
    const int wr   = w >> 1;     // co half (0/1)
    const int wc   = w & 1;      // pix half (0/1)

    __shared__ bf16 Wbuf[2][8192];   // 2 x 16 KB  [co 0..127][ci-oct swz]
    __shared__ bf16 Xbuf[2][8192];   // 2 x 16 KB  [pix 0..127][ci-oct swz]

    // W staging source: wimg page is the exact LDS byte image
    const char* wsrcL = (const char*)wimg + ((size_t)(s * NSTEP) << 14)
                      + (w << 12) + (lane << 4);

    // X staging sources: wave w stages pix w*32 .. w*32+31, 4 chunks
    const char *x0, *x1, *x2, *x3;
    #pragma unroll
    for (int q = 0; q < 4; ++q) {
        int pix = w * 32 + q * 8 + (lane >> 3);
        int g   = tile * TILE + pix;
        if (g >= GPIX) g = GPIX - 1;      // clamp; garbage cols discarded
        int b2 = g / NPIX;
        int rr = g - b2 * NPIX;
        int oy = rr / WOc;
        int ox = rr - oy * WOc;
        int m  = (lane & 7) ^ (pix & 7);  // source ci-octet for this slot
        const char* ptr = (const char*)xt
            + ((((size_t)(b2 * Sn + s) << 10) + oy * 32 + ox) << 7) + (m << 4);
        if (q == 0) x0 = ptr; else if (q == 1) x1 = ptr;
        else if (q == 2) x2 = ptr; else x3 = ptr;
    }

    f32x16 acc[2][2];
    #pragma unroll
    for (int i = 0; i < 2; ++i)
        #pragma unroll
        for (int j = 0; j < 2; ++j)
            #pragma unroll
            for (int k = 0; k < 16; ++k)
                acc[i][j][k] = 0.f;

    #define STAGE(stepc, b)                                                  \
    {                                                                        \
        const char* ws_ = wsrcL + ((stepc) << 14);                           \
        char* wl_ = (char*)(&Wbuf[(b)][0]) + (w << 12);                      \
        gl16(ws_,        wl_);                                               \
        gl16(ws_ + 1024, wl_ + 1024);                                        \
        gl16(ws_ + 2048, wl_ + 2048);                                        \
        gl16(ws_ + 3072, wl_ + 3072);                                        \
        const int roff_ = (((stepc) / 3) * 32 + ((stepc) % 3)) * 128;        \
        char* xl_ = (char*)(&Xbuf[(b)][0]) + (w << 12);                      \
        gl16(x0 + roff_, xl_);                                               \
        gl16(x1 + roff_, xl_ + 1024);                                        \
        gl16(x2 + roff_, xl_ + 2048);                                        \
        gl16(x3 + roff_, xl_ + 3072);                                        \
    }

    #define COMPUTE(b)                                                       \
    {                                                                        \
        const bf16* Wl_ = &Wbuf[(b)][0];                                     \
        const bf16* Xl_ = &Xbuf[(b)][0];                                     \
        _Pragma("unroll")                                                    \
        for (int kc = 0; kc < 4; ++kc) {                                     \
            const int oct_ = ((kc << 1) + (lane >> 5)) ^ (lane & 7);         \
            bf16x8 af0 = *reinterpret_cast<const bf16x8*>(                   \
                Wl_ + ((wr * 64 + (lane & 31)) << 6) + (oct_ << 3));         \
            bf16x8 af1 = *reinterpret_cast<const bf16x8*>(                   \
                Wl_ + ((wr * 64 + 32 + (lane & 31)) << 6) + (oct_ << 3));    \
            bf16x8 bf0 = *reinterpret_cast<const bf16x8*>(                   \
                Xl_ + ((wc * 64 + (lane & 31)) << 6) + (oct_ << 3));         \
            bf16x8 bf1 = *reinterpret_cast<const bf16x8*>(                   \
                Xl_ + ((wc * 64 + 32 + (lane & 31)) << 6) + (oct_ << 3));    \
            acc[0][0] = __builtin_amdgcn_mfma_f32_32x32x16_bf16(af0, bf0, acc[0][0], 0, 0, 0); \
            acc[0][1] = __builtin_amdgcn_mfma_f32_32x32x16_bf16(af0, bf1, acc[0][1], 0, 0, 0); \
            acc[1][0] = __builtin_amdgcn_mfma_f32_32x32x16_bf16(af1, bf0, acc[1][0], 0, 0, 0); \
            acc[1][1] = __builtin_amdgcn_mfma_f32_32x32x16_bf16(af1, bf1, acc[1][1], 0, 0, 0); \
        }                                                                    \
    }

    // prologue: two stages in flight
    STAGE(0, 0);
    STAGE(1, 1);

    #define ITER(tt, b)                                                      \
        asm volatile("s_waitcnt vmcnt(8)" ::: "memory");                     \
        __builtin_amdgcn_s_barrier();                                        \
        __builtin_amdgcn_sched_barrier(0);                                   \
        COMPUTE(b);                                                          \
        __builtin_amdgcn_sched_barrier(0);                                   \
        __builtin_amdgcn_s_barrier();                                        \
        STAGE((tt) + 2, b);

    ITER(0, 0)
    ITER(1, 1)
    ITER(2, 0)
    ITER(3, 1)
    ITER(4, 0)
    ITER(5, 1)
    ITER(6, 0)
    // step 7 (buf 1): no further stage
    asm volatile("s_waitcnt vmcnt(8)" ::: "memory");
    __builtin_amdgcn_s_barrier();
    __builtin_amdgcn_sched_barrier(0);
    COMPUTE(1);
    // step 8 (buf 0): final, drain
    asm volatile("s_waitcnt vmcnt(0)" ::: "memory");
    __builtin_amdgcn_s_barrier();
    __builtin_amdgcn_sched_barrier(0);
    COMPUTE(0);

    #undef ITER
    #undef COMPUTE
    #undef STAGE

    // ---- epilogue: 32x32 C/D: col(pix)=lane&31, row(co)=(reg&3)+8*(reg>>2)+4*(lane>>5)
    const int colp = lane & 31;
    const int hi   = lane >> 5;
    #pragma unroll
    for (int ti = 0; ti < 2; ++ti) {
        float bs[16];
        #pragma unroll
        for (int reg = 0; reg < 16; ++reg) {
            int co = wr * 64 + ti * 32 + (reg & 3) + 8 * (reg >> 2) + 4 * hi;
            bs[reg] = bq[s * COUTc + co];
        }
        #pragma unroll
        for (int tj = 0; tj < 2; ++tj) {
            int gg = tile * TILE + wc * 64 + tj * 32 + colp;
            if (gg >= GPIX) continue;
            int b2 = gg / NPIX;
            int r2 = gg - b2 * NPIX;
            float* ob = out + (size_t)(b2 * Sn + s) * (COUTc * NPIX) + r2;
            #pragma unroll
            for (int reg = 0; reg < 16; ++reg) {
                int co = wr * 64 + ti * 32 + (reg & 3) + 8 * (reg >> 2) + 4 * hi;
                ob[co * NPIX] = acc[ti][tj][reg] + bs[reg];
            }
        }
    }

    // ---- KL finalize (block 0, wave 0, lane-parallel over NSLOT slots)
    if (bid == 0 && w == 0) {
        float ls = 0.f, sq = 0.f;
        for (int i2 = lane; i2 < NSLOT; i2 += 64) {
            ls += slots[2 * i2];
            sq += slots[2 * i2 + 1];
        }
        #pragma unroll
        for (int off = 32; off > 0; off >>= 1) {
            ls += __shfl_down(ls, off);
            sq += __shfl_down(sq, off);
        }
        if (lane == 0)
            *klout = -ls + 0.91893853320467274f * (float)Pc + 0.5f * sq;
    }
}

// ---------------------------------------------------------------------------
extern "C" void kernel_launch(void* const* d_in, const int* in_sizes, int n_in,
                              void* d_out, int out_size, void* d_ws, size_t ws_size,
                              hipStream_t stream) {
    const float* x     = (const float*)d_in[0];
    const float* e     = (const float*)d_in[1];
    const float* mu_w  = (const float*)d_in[2];
    const float* rho_w = (const float*)d_in[3];
    const float* mu_b  = (const float*)d_in[4];
    const float* rho_b = (const float*)d_in[5];
    float* out = (float*)d_out;

    // workspace layout
    bf16*  wimg  = (bf16*)d_ws;                         // 1,179,648 B
    float* bq    = (float*)((char*)d_ws + 1179648);     // 4,096 B
    float* slots = (float*)((char*)d_ws + 1183744);     // 1,032 B (pad to 4K)
    bf16*  xt    = (bf16*)((char*)d_ws + 1187840);      // 8,388,608 B

    prep_all<<<dim3(641), dim3(256), 0, stream>>>(
        x, e, mu_w, rho_w, mu_b, rho_b, xt, wimg, bq, slots);

    conv_mfma<<<dim3(NT2 * Sn), dim3(256), 0, stream>>>(
        xt, wimg, bq, slots, out, out + (out_size - 1));
}